// Round 1
// baseline (1248.332 us; speedup 1.0000x reference)
//
#include <hip/hip_runtime.h>
#include <hip/hip_bf16.h>
#include <stdint.h>

// Problem constants (fixed by setup_inputs)
#define IN_DIM   512
#define OUT_DIM  512
#define NSEG     65536
#define NROWS    409600
#define NIN      51200

typedef __attribute__((ext_vector_type(8))) short  short8v;   // 8 x bf16 (4 VGPRs)
typedef __attribute__((ext_vector_type(4))) float  float4v;   // MFMA C/D

static __device__ inline short f2bf(float f) {
    union { float f; unsigned int u; } c; c.f = f;
    unsigned int u = c.u;
    unsigned int r = (u + 0x7FFFu + ((u >> 16) & 1u)) >> 16;   // RNE
    return (short)(unsigned short)r;
}

// async global -> LDS, 16B per lane (m97 pattern). LDS dest must be
// wave-uniform base + lane*16; global src is per-lane.
static __device__ __forceinline__ void gload16(const void* g, void* l) {
    __builtin_amdgcn_global_load_lds(
        (const __attribute__((address_space(1))) void*)g,
        (__attribute__((address_space(3))) void*)l,
        16, 0, 0);
}

// ---------------------------------------------------------------- zero counts
__global__ __launch_bounds__(256) void zero_counts(int* __restrict__ counts) {
    int i = blockIdx.x * 256 + threadIdx.x;
    if (i < NSEG) counts[i] = 0;
}

// ---------------------------------------------------------------- histogram
__global__ __launch_bounds__(256) void hist_kernel(const int* __restrict__ idx,
                                                   int* __restrict__ counts) {
    int i = blockIdx.x * 256 + threadIdx.x;
    if (i < NROWS) atomicAdd(&counts[idx[i]], 1);
}

// ---------------------------------------------------------------- scan
// Single block, 1024 threads, each owns 64 consecutive buckets.
// Produces exclusive offsets offs[0..NSEG] and initializes cursor = offs.
__global__ __launch_bounds__(1024) void scan_kernel(const int* __restrict__ counts,
                                                    int* __restrict__ offs,
                                                    int* __restrict__ cursor) {
    __shared__ int part[1024];
    const int t = threadIdx.x;
    const int base = t * 64;
    int local[64];
    int sum = 0;
#pragma unroll
    for (int k = 0; k < 64; ++k) { local[k] = counts[base + k]; sum += local[k]; }
    part[t] = sum;
    __syncthreads();
    // Hillis-Steele inclusive scan over 1024 partials
    for (int off = 1; off < 1024; off <<= 1) {
        int v = (t >= off) ? part[t - off] : 0;
        __syncthreads();
        part[t] += v;
        __syncthreads();
    }
    int running = part[t] - sum;   // exclusive prefix for this thread's chunk
#pragma unroll
    for (int k = 0; k < 64; ++k) {
        offs[base + k]   = running;
        cursor[base + k] = running;
        running += local[k];
    }
    if (t == 1023) offs[NSEG] = running;   // == NROWS
}

// ---------------------------------------------------------------- reorder
// Also precomputes wperm[pos] = w[i % NIN] so the gather hot loop has no
// dependent w load and no integer modulo.
__global__ __launch_bounds__(256) void reorder_kernel(const int* __restrict__ idx,
                                                      const float* __restrict__ w,
                                                      int* __restrict__ cursor,
                                                      int* __restrict__ order,
                                                      float* __restrict__ wperm) {
    int i = blockIdx.x * 256 + threadIdx.x;
    if (i < NROWS) {
        int pos = atomicAdd(&cursor[idx[i]], 1);
        order[pos] = i;
        wperm[pos] = w[i % NIN];
    }
}

// ---------------------------------------------------------------- gather-reduce
// One wave per segment: accumulate wperm[j]*h[order[j],:] over the segment's
// rows in f32 registers, 2-deep software pipeline (next row's loads in flight
// while current row's FMAs retire). Store 512-wide result row as bf16.
#define ACC8() do { \
    a0.x += v0.x * wv; a0.y += v0.y * wv; a0.z += v0.z * wv; a0.w += v0.w * wv; \
    a1.x += v1.x * wv; a1.y += v1.y * wv; a1.z += v1.z * wv; a1.w += v1.w * wv; } while (0)

__global__ __launch_bounds__(256) void gather_reduce(const float* __restrict__ h,
                                                     const float* __restrict__ wperm,
                                                     const int*   __restrict__ order,
                                                     const int*   __restrict__ offs,
                                                     short*       __restrict__ agg_bf) {
    int seg  = blockIdx.x * 4 + (threadIdx.x >> 6);
    int lane = threadIdx.x & 63;
    int j    = offs[seg];
    int end  = offs[seg + 1];

    float4 a0 = make_float4(0.f, 0.f, 0.f, 0.f);
    float4 a1 = make_float4(0.f, 0.f, 0.f, 0.f);

    if (j < end) {
        int    row = order[j];
        float  wv  = wperm[j];
        const float4* hr = (const float4*)(h + (size_t)row * IN_DIM) + 2 * lane;
        float4 v0 = hr[0];
        float4 v1 = hr[1];
        for (++j; j < end; ++j) {
            int    nrow = order[j];
            float  nwv  = wperm[j];
            const float4* nhr = (const float4*)(h + (size_t)nrow * IN_DIM) + 2 * lane;
            float4 u0 = nhr[0];
            float4 u1 = nhr[1];
            ACC8();
            wv = nwv; v0 = u0; v1 = u1;
        }
        ACC8();
    }

    short8v pk;
    pk[0] = f2bf(a0.x); pk[1] = f2bf(a0.y); pk[2] = f2bf(a0.z); pk[3] = f2bf(a0.w);
    pk[4] = f2bf(a1.x); pk[5] = f2bf(a1.y); pk[6] = f2bf(a1.z); pk[7] = f2bf(a1.w);
    *(short8v*)(agg_bf + (size_t)seg * IN_DIM + lane * 8) = pk;
}

// ---------------------------------------------------------------- W -> bf16
__global__ __launch_bounds__(256) void cvt_w(const float4* __restrict__ src,
                                             short* __restrict__ dst, int n4) {
    int i = blockIdx.x * 256 + threadIdx.x;
    if (i < n4) {
        float4 v = src[i];
        union { short s[4]; uint64_t u; } p;
        p.s[0] = f2bf(v.x); p.s[1] = f2bf(v.y);
        p.s[2] = f2bf(v.z); p.s[3] = f2bf(v.w);
        *(uint64_t*)(dst + (size_t)i * 4) = p.u;
    }
}

// ---------------------------------------------------------------- GEMM
// out[65536,512] = agg_bf @ Wb^T + b, bf16 MFMA 16x16x32.
// m97 structure: 128x128 tile, BK=64, linear [128][64] LDS, staged via
// global_load_lds width=16 (no VGPR round-trip). 4 waves (2x2), 4x4 frags.
#define BM 128
#define BN 128
#define BK 64

__global__ __launch_bounds__(256) void gemm_bf16(const short* __restrict__ Ab,
                                                 const short* __restrict__ Wb,
                                                 const float* __restrict__ bias,
                                                 float* __restrict__ out) {
    __shared__ short As[BM * BK];   // 16 KiB, row stride 64 shorts (128B)
    __shared__ short Bs[BN * BK];   // 16 KiB

    const int t    = threadIdx.x;
    const int m0   = blockIdx.y * BM;
    const int n0   = blockIdx.x * BN;
    const int lane = t & 63;
    const int wv   = t >> 6;
    const int wm   = wv >> 1, wn = wv & 1;
    const int fm   = lane & 15;    // frag row/col within 16
    const int fq   = lane >> 4;    // quad 0..3

    float4v acc[4][4];
#pragma unroll
    for (int i = 0; i < 4; ++i)
#pragma unroll
        for (int j = 0; j < 4; ++j) acc[i][j] = (float4v){0.f, 0.f, 0.f, 0.f};

    for (int kt = 0; kt < IN_DIM; kt += BK) {
        __syncthreads();   // previous tile fully consumed
        // Stage A: 128 rows x 64 k (16 KiB) = 4 issues x 256 lanes x 16B.
        // LDS dest linear: thread c -> bytes [c*16, c*16+16) == wave-uniform
        // base + lane*16. Global src: row = c>>3, 16B-chunk = c&7.
#pragma unroll
        for (int r = 0; r < 4; ++r) {
            int c   = r * 256 + t;
            int row = c >> 3, ch = c & 7;
            gload16(Ab + (size_t)(m0 + row) * IN_DIM + kt + ch * 8, As + c * 8);
        }
#pragma unroll
        for (int r = 0; r < 4; ++r) {
            int c   = r * 256 + t;
            int row = c >> 3, ch = c & 7;
            gload16(Wb + (size_t)(n0 + row) * IN_DIM + kt + ch * 8, Bs + c * 8);
        }
        __syncthreads();   // compiler drains vmcnt(0) before s_barrier
#pragma unroll
        for (int ks = 0; ks < 2; ++ks) {
            short8v a[4], b[4];
#pragma unroll
            for (int mt = 0; mt < 4; ++mt)
                a[mt] = *(const short8v*)&As[(wm * 64 + mt * 16 + fm) * BK + ks * 32 + fq * 8];
#pragma unroll
            for (int nt = 0; nt < 4; ++nt)
                b[nt] = *(const short8v*)&Bs[(wn * 64 + nt * 16 + fm) * BK + ks * 32 + fq * 8];
#pragma unroll
            for (int mt = 0; mt < 4; ++mt)
#pragma unroll
                for (int nt = 0; nt < 4; ++nt)
                    acc[mt][nt] = __builtin_amdgcn_mfma_f32_16x16x32_bf16(a[mt], b[nt], acc[mt][nt], 0, 0, 0);
        }
    }

    // Epilogue: C/D layout col = lane&15, row = quad*4 + reg
#pragma unroll
    for (int nt = 0; nt < 4; ++nt) {
        int col = n0 + wn * 64 + nt * 16 + fm;
        float bv = bias[col];
#pragma unroll
        for (int mt = 0; mt < 4; ++mt) {
            int rowb = m0 + wm * 64 + mt * 16 + fq * 4;
#pragma unroll
            for (int r = 0; r < 4; ++r)
                out[(size_t)(rowb + r) * OUT_DIM + col] = acc[mt][nt][r] + bv;
        }
    }
}

// ---------------------------------------------------------------- launch
extern "C" void kernel_launch(void* const* d_in, const int* in_sizes, int n_in,
                              void* d_out, int out_size, void* d_ws, size_t ws_size,
                              hipStream_t stream) {
    const float* h     = (const float*)d_in[0];
    const float* w     = (const float*)d_in[1];
    const float* lin_w = (const float*)d_in[2];
    const float* lin_b = (const float*)d_in[3];
    const int*   idx   = (const int*)d_in[4];

    // Workspace layout (all offsets 256-aligned):
    char* ws = (char*)d_ws;
    short* agg_bf = (short*)ws;                                   // 64 MiB
    size_t off = (size_t)NSEG * IN_DIM * sizeof(short);
    short* Wb = (short*)(ws + off);      off += (size_t)OUT_DIM * IN_DIM * sizeof(short); // 512 KiB
    int* counts = (int*)(ws + off);      off += (size_t)NSEG * sizeof(int);
    int* offs   = (int*)(ws + off);      off += (size_t)(NSEG + 64) * sizeof(int);
    int* cursor = (int*)(ws + off);      off += (size_t)NSEG * sizeof(int);
    int* order  = (int*)(ws + off);      off += (size_t)NROWS * sizeof(int);
    float* wperm = (float*)(ws + off);   off += (size_t)NROWS * sizeof(float);
    float* out = (float*)d_out;

    zero_counts<<<NSEG / 256, 256, 0, stream>>>(counts);
    hist_kernel<<<NROWS / 256, 256, 0, stream>>>(idx, counts);
    scan_kernel<<<1, 1024, 0, stream>>>(counts, offs, cursor);
    reorder_kernel<<<NROWS / 256, 256, 0, stream>>>(idx, w, cursor, order, wperm);
    gather_reduce<<<NSEG / 4, 256, 0, stream>>>(h, wperm, order, offs, agg_bf);
    cvt_w<<<(OUT_DIM * IN_DIM / 4 + 255) / 256, 256, 0, stream>>>(
        (const float4*)lin_w, Wb, OUT_DIM * IN_DIM / 4);
    dim3 grid(OUT_DIM / BN, NSEG / BM);
    gemm_bf16<<<grid, 256, 0, stream>>>(agg_bf, Wb, lin_b, out);
}